// Round 22
// baseline (171.308 us; speedup 1.0000x reference)
//
#include <hip/hip_runtime.h>
#include <hip/hip_bf16.h>

#define DEV __device__ __forceinline__

typedef float f32x4 __attribute__((ext_vector_type(4)));
typedef unsigned short u16x4 __attribute__((ext_vector_type(4)));
typedef unsigned short u16x8 __attribute__((ext_vector_type(8)));
typedef __bf16 bf16x8 __attribute__((ext_vector_type(8)));

DEV unsigned short f2b(float f) { __bf16 h = (__bf16)f; return __builtin_bit_cast(unsigned short, h); }
DEV bf16x8 asbf8(u16x8 v) { return __builtin_bit_cast(bf16x8, v); }

#define MFMA(a, b, c) __builtin_amdgcn_mfma_f32_16x16x32_bf16((a), (b), (c), 0, 0, 0)

// Problem constants
// B=8, L=8192, S=512, DQ=256, DC=768, H=8, DH=64, INNER=512
// QSCALE = (1/sqrt(64)) * log2(e): scores computed directly in log2 domain.
constexpr float QSCALE = 0.18033688011112042f;
// Fixed softmax shift (log2 domain), folded into the QK^T accumulator init.
constexpr float MFIX = 20.0f;

// ---------------------------------------------------------------------------
// K0: weight convert/transpose to bf16 (unchanged; WqT feeds fused attn now).
// ---------------------------------------------------------------------------
__global__ __launch_bounds__(256) void convert_weights(
    const float* __restrict__ Wq, const float* __restrict__ Wk,
    const float* __restrict__ Wv, const float* __restrict__ Wo,
    unsigned short* __restrict__ WqT, unsigned short* __restrict__ WkvT,
    unsigned short* __restrict__ WoT)
{
  int i = blockIdx.x * 256 + threadIdx.x;
  if (i < 131072) {
    int n = i >> 8, k = i & 255;                 // WqT [512][256]
    WqT[i] = f2b(Wq[k * 512 + n] * QSCALE);
  } else if (i < 131072 + 786432) {
    int j = i - 131072;
    int n = j / 768, k = j - n * 768;            // WkvT [1024][768]
    float v = (n < 512) ? Wk[k * 512 + n] : Wv[k * 512 + (n - 512)];
    WkvT[j] = f2b(v);
  } else {
    int j = i - 917504;
    int n = j >> 9, k = j & 511;                 // WoT [256][512]
    WoT[j] = f2b(Wo[k * 256 + n]);
  }
}

// ---------------------------------------------------------------------------
// KV projection (r20/r21 proven chunk-staged body, KV path only; grid 512).
// ---------------------------------------------------------------------------
__global__ __launch_bounds__(256, 4) void kv_proj(
    const float* __restrict__ ctx, const unsigned short* __restrict__ WkvT,
    unsigned short* __restrict__ Kws, unsigned short* __restrict__ VTws)
{
  constexpr int KDIM = 768, NCOLS = 128;
  constexpr int WC = NCOLS / 4;
  constexpr int NCT = WC / 16;
  constexpr int NCH = KDIM / 256;
  constexpr int RS = 264;
  __shared__ __align__(16) unsigned short Lb[64 * 264];
  const int t = threadIdx.x;
  const int wid = t >> 6, lane = t & 63;
  const int q = lane & 15, g = lane >> 4;
  const int bx = blockIdx.x & 63, by = blockIdx.x >> 6;
  const int row0 = bx * 64;
  const int wcol = by * NCOLS + wid * WC;

  const int ar0 = t >> 3, akc = (t & 7) * 4;

  const unsigned short* brow[NCT];
  #pragma unroll
  for (int ct = 0; ct < NCT; ++ct)
    brow[ct] = WkvT + (size_t)(wcol + ct * 16 + q) * KDIM + g * 8;

  f32x4 acc[4][NCT];
  #pragma unroll
  for (int i = 0; i < 4; ++i)
    #pragma unroll
    for (int j = 0; j < NCT; ++j) acc[i][j] = {0.f, 0.f, 0.f, 0.f};

  #pragma unroll 1
  for (int ch = 0; ch < NCH; ++ch) {
    const int kb = ch * 256;
    if (ch) __syncthreads();
    #pragma unroll
    for (int stp = 0; stp < 8; ++stp) {
      const int col = akc + 32 * stp;
      f32x4 v0 = *(const f32x4*)(ctx + (size_t)(row0 + ar0) * KDIM + kb + col);
      f32x4 v1 = *(const f32x4*)(ctx + (size_t)(row0 + 32 + ar0) * KDIM + kb + col);
      u16x4 w0, w1;
      w0[0] = f2b(v0[0]); w0[1] = f2b(v0[1]); w0[2] = f2b(v0[2]); w0[3] = f2b(v0[3]);
      w1[0] = f2b(v1[0]); w1[1] = f2b(v1[1]); w1[2] = f2b(v1[2]); w1[3] = f2b(v1[3]);
      *(u16x4*)(Lb + ar0 * RS + col) = w0;
      *(u16x4*)(Lb + (32 + ar0) * RS + col) = w1;
    }
    __syncthreads();

    #pragma unroll
    for (int st = 0; st < 8; ++st) {
      const int k0 = st * 32;
      bf16x8 af[4];
      #pragma unroll
      for (int rt = 0; rt < 4; ++rt)
        af[rt] = asbf8(*(const u16x8*)(Lb + (rt * 16 + q) * RS + k0 + g * 8));
      bf16x8 bf[NCT];
      #pragma unroll
      for (int ct = 0; ct < NCT; ++ct)
        bf[ct] = asbf8(*(const u16x8*)(brow[ct] + kb + k0));
      #pragma unroll
      for (int ct = 0; ct < NCT; ++ct)
        #pragma unroll
        for (int rt = 0; rt < 4; ++rt)
          acc[rt][ct] = MFMA(af[rt], bf[ct], acc[rt][ct]);
    }
  }

  const int bb = row0 >> 9, s0 = row0 & 511;
  #pragma unroll
  for (int ct = 0; ct < NCT; ++ct) {
    int col = wcol + ct * 16 + q;
    if (col < 512) {
      int hh = col >> 6, d = col & 63;
      #pragma unroll
      for (int rt = 0; rt < 4; ++rt)
        #pragma unroll
        for (int r = 0; r < 4; ++r) {
          int s = s0 + rt * 16 + g * 4 + r;
          Kws[(((size_t)bb * 8 + hh) * 512 + s) * 64 + d] = f2b(acc[rt][ct][r]);
        }
    } else {
      int c2 = col - 512, hh = c2 >> 6, d = c2 & 63;
      #pragma unroll
      for (int rt = 0; rt < 4; ++rt)
        #pragma unroll
        for (int r = 0; r < 4; ++r) {
          int s = s0 + rt * 16 + g * 4 + r;
          VTws[(((size_t)bb * 8 + hh) * 64 + d) * 512 + s] = f2b(acc[rt][ct][r]);
        }
    }
  }
}

// ---------------------------------------------------------------------------
// K2: fused Q-compute + attention.
//  Item decode (XCD class c = (b+tile)&7): the 8 h-items sharing an x-tile
//  have bids differing by 8 -> same XCD + adjacent dispatch (x L2-shared);
//  each class gets ~1/8 of every batch's valid tiles (balanced).
//  Q-compute per wave: direct x loads (A-frag, proj convention) @ WqT h-slice
//  (B-frag) -> acc_q D-layout Q[rt*16+g*4+r][ct*16+q] -> per-wave LDS bounce
//  Qt[32][72] (stride 72: b128 read granule 9q mod 16 = full permutation) ->
//  qf frags in the exact layout the proven K/V loop expects. Same-wave LDS
//  RAW (no barrier needed); one block barrier before smem is reused for K/V.
//  K/V loop + epilogue: r14/r21 verbatim (indices re-based onto carved smem).
// ---------------------------------------------------------------------------
__global__ __launch_bounds__(256, 4) void attn_kernel(
    const float* __restrict__ x, const unsigned short* __restrict__ WqT,
    const unsigned short* __restrict__ Kw, const unsigned short* __restrict__ VTw,
    const int* __restrict__ seq_lens, unsigned short* __restrict__ AO)
{
  const int bid = blockIdx.x;
  const int c = bid & 7;                  // XCD class
  const int u = bid >> 3;
  const int h = u & 7;
  const int k2 = u >> 3;                  // 0..63
  const int b = k2 >> 3;
  const int jj = k2 & 7;
  const int tile = ((c - b) & 7) + 8 * jj;

  const int sl = seq_lens[b];
  const int qbase0 = tile * 128;
  if (qbase0 >= sl) return;               // dead item: exit immediately

  const int wid = threadIdx.x >> 6, lane = threadIdx.x & 63;
  const int q = lane & 15, g = lane >> 4;

  // smem union: Q-bounce Qt[4 waves][32][72] u16 (18432 B), then reused as
  // Ks[2][32*64] + Vs[2][64*32] (16384 B).
  __shared__ __align__(16) unsigned short smem[9216];
  unsigned short* Ksp = smem;             // Ks[buf] = Ksp + buf*2048
  unsigned short* Vsp = smem + 4096;      // Vs[buf] = Vsp + buf*2048

  // staging geometry (identical to r4/r7 per 32-key tile)
  const int krow  = (wid << 3) + (lane >> 3);          // K row 0..31
  const int kslot = (lane & 7) ^ (lane >> 3);          // stored 16B slot (swz)
  const int vd    = (wid << 4) + (lane >> 2);          // V d-row 0..63
  const int vc    = lane & 3;                          // natural 8-elem chunk
  const int vswz  = (vd >> 1) & 3;
  const int vs0   = (((2 * vc) & 3) ^ vswz) * 8 + ((vc >> 1) * 4);      // elems
  const int vs1   = (((2 * vc + 1) & 3) ^ vswz) * 8 + ((vc >> 1) * 4);  // elems
  const int vrslot = (g ^ ((q >> 1) & 3)) * 8;         // va stored slot (elems)

  const int qbase = qbase0 + wid * 32;
  const bool wactive = qbase < sl;

  const unsigned short* Kb = Kw + ((size_t)b * 8 + h) * (512 * 64);
  const unsigned short* Vb = VTw + ((size_t)b * 8 + h) * (64 * 512);

  // ---- Q-compute: qf[2][2] = (x @ Wq)[qbase.., h*64..] --------------------
  bf16x8 qf[2][2];
  {
    unsigned short* Qt = smem + wid * (32 * 72);       // per-wave region
    if (wactive) {
      f32x4 acc_q[2][4];
      #pragma unroll
      for (int rt = 0; rt < 2; ++rt)
        #pragma unroll
        for (int ct = 0; ct < 4; ++ct) acc_q[rt][ct] = {0.f, 0.f, 0.f, 0.f};

      const float* xb0 = x + ((size_t)b * 8192 + qbase) * 256;
      #pragma unroll
      for (int ks = 0; ks < 8; ++ks) {
        const int k0 = ks * 32;
        bf16x8 af[2];
        #pragma unroll
        for (int rt = 0; rt < 2; ++rt) {
          const float* px = xb0 + (size_t)(rt * 16 + q) * 256 + k0 + g * 8;
          f32x4 lo = *(const f32x4*)px;
          f32x4 hi = *(const f32x4*)(px + 4);
          u16x8 uu;
          uu[0] = f2b(lo[0]); uu[1] = f2b(lo[1]); uu[2] = f2b(lo[2]); uu[3] = f2b(lo[3]);
          uu[4] = f2b(hi[0]); uu[5] = f2b(hi[1]); uu[6] = f2b(hi[2]); uu[7] = f2b(hi[3]);
          af[rt] = asbf8(uu);
        }
        bf16x8 wf[4];
        #pragma unroll
        for (int ct = 0; ct < 4; ++ct)
          wf[ct] = asbf8(*(const u16x8*)(WqT + (size_t)(h * 64 + ct * 16 + q) * 256 + k0 + g * 8));
        #pragma unroll
        for (int ct = 0; ct < 4; ++ct)
          #pragma unroll
          for (int rt = 0; rt < 2; ++rt)
            acc_q[rt][ct] = MFMA(af[rt], wf[ct], acc_q[rt][ct]);
      }
      // D layout: acc_q[rt][ct][r] = Q[qbase + rt*16 + g*4 + r][h*64 + ct*16 + q]
      #pragma unroll
      for (int rt = 0; rt < 2; ++rt)
        #pragma unroll
        for (int ct = 0; ct < 4; ++ct)
          #pragma unroll
          for (int r = 0; r < 4; ++r)
            Qt[(rt * 16 + g * 4 + r) * 72 + ct * 16 + q] = f2b(acc_q[rt][ct][r]);
      // same-wave RAW read (compiler orders via lgkmcnt)
      #pragma unroll
      for (int qt = 0; qt < 2; ++qt)
        #pragma unroll
        for (int dc = 0; dc < 2; ++dc)
          qf[qt][dc] = asbf8(*(const u16x8*)(Qt + (qt * 16 + q) * 72 + dc * 32 + g * 8));
    }
  }
  __syncthreads();   // Qt dead for all waves; smem now reused as Ks/Vs

  f32x4 acc[2][4];
  float lsum[2] = {0.f, 0.f};
  #pragma unroll
  for (int qt = 0; qt < 2; ++qt)
    #pragma unroll
    for (int dt = 0; dt < 4; ++dt) acc[qt][dt] = {0.f, 0.f, 0.f, 0.f};

  // ---- prologue: stage step 0 into buffer 0 -------------------------------
  {
    u16x8 kr = *(const u16x8*)(Kb + krow * 64 + (lane & 7) * 8);
    u16x8 vr = *(const u16x8*)(Vb + vd * 512 + vc * 8);
    *(u16x8*)(&Ksp[krow * 64 + kslot * 8]) = kr;
    u16x4 vlo, vhi;
    vlo[0] = vr[0]; vlo[1] = vr[1]; vlo[2] = vr[2]; vlo[3] = vr[3];
    vhi[0] = vr[4]; vhi[1] = vr[5]; vhi[2] = vr[6]; vhi[3] = vr[7];
    *(u16x4*)(&Vsp[vd * 32 + vs0]) = vlo;
    *(u16x4*)(&Vsp[vd * 32 + vs1]) = vhi;
  }
  __syncthreads();

  #pragma unroll 2
  for (int st = 0; st < 16; ++st) {
    const int cur = st & 1;
    const int scn = (st + 1) * 32;

    u16x8 kn, vn;
    if (st < 15) {
      kn = *(const u16x8*)(Kb + (scn + krow) * 64 + (lane & 7) * 8);
      vn = *(const u16x8*)(Vb + vd * 512 + scn + vc * 8);
    }

    if (wactive) {
      bf16x8 kf[2][2];
      #pragma unroll
      for (int tt = 0; tt < 2; ++tt)
        #pragma unroll
        for (int dc = 0; dc < 2; ++dc)
          kf[tt][dc] = asbf8(*(const u16x8*)(
              &Ksp[cur * 2048 + (tt * 16 + q) * 64 + ((dc * 4 + g) ^ (q & 7)) * 8]));

      bf16x8 va[4];
      #pragma unroll
      for (int dt = 0; dt < 4; ++dt)
        va[dt] = asbf8(*(const u16x8*)(&Vsp[cur * 2048 + (dt * 16 + q) * 32 + vrslot]));

      #pragma unroll
      for (int qt = 0; qt < 2; ++qt) {
        f32x4 t0 = {-MFIX, -MFIX, -MFIX, -MFIX};
        f32x4 t1 = {-MFIX, -MFIX, -MFIX, -MFIX};
        t0 = MFMA(kf[0][0], qf[qt][0], t0);
        t0 = MFMA(kf[0][1], qf[qt][1], t0);
        t1 = MFMA(kf[1][0], qf[qt][0], t1);
        t1 = MFMA(kf[1][1], qf[qt][1], t1);

        float p0 = __builtin_amdgcn_exp2f(t0[0]);
        float p1 = __builtin_amdgcn_exp2f(t0[1]);
        float p2 = __builtin_amdgcn_exp2f(t0[2]);
        float p3 = __builtin_amdgcn_exp2f(t0[3]);
        float p4 = __builtin_amdgcn_exp2f(t1[0]);
        float p5 = __builtin_amdgcn_exp2f(t1[1]);
        float p6 = __builtin_amdgcn_exp2f(t1[2]);
        float p7 = __builtin_amdgcn_exp2f(t1[3]);
        lsum[qt] += ((p0 + p1) + (p2 + p3)) + ((p4 + p5) + (p6 + p7));

        u16x8 pu;
        pu[0] = f2b(p0); pu[1] = f2b(p1); pu[2] = f2b(p2); pu[3] = f2b(p3);
        pu[4] = f2b(p4); pu[5] = f2b(p5); pu[6] = f2b(p6); pu[7] = f2b(p7);
        bf16x8 pb = asbf8(pu);

        #pragma unroll
        for (int dt = 0; dt < 4; ++dt)
          acc[qt][dt] = MFMA(va[dt], pb, acc[qt][dt]);
      }
    }

    if (st < 15) {
      const int nb = cur ^ 1;
      *(u16x8*)(&Ksp[nb * 2048 + krow * 64 + kslot * 8]) = kn;
      u16x4 vlo, vhi;
      vlo[0] = vn[0]; vlo[1] = vn[1]; vlo[2] = vn[2]; vlo[3] = vn[3];
      vhi[0] = vn[4]; vhi[1] = vn[5]; vhi[2] = vn[6]; vhi[3] = vn[7];
      *(u16x4*)(&Vsp[nb * 2048 + vd * 32 + vs0]) = vlo;
      *(u16x4*)(&Vsp[nb * 2048 + vd * 32 + vs1]) = vhi;
    }
    __syncthreads();
  }

  if (wactive) {
    #pragma unroll
    for (int qt = 0; qt < 2; ++qt) {
      float lt = lsum[qt];
      lt += __shfl_xor(lt, 16);
      lt += __shfl_xor(lt, 32);
      float inv = __builtin_amdgcn_rcpf(lt);
      size_t ro = ((size_t)b * 8192 + qbase + qt * 16 + q) * 512 + h * 64;
      #pragma unroll
      for (int dt = 0; dt < 4; ++dt) {
        u16x4 o;
        o[0] = f2b(acc[qt][dt][0] * inv);
        o[1] = f2b(acc[qt][dt][1] * inv);
        o[2] = f2b(acc[qt][dt][2] * inv);
        o[3] = f2b(acc[qt][dt][3] * inv);
        *(u16x4*)(AO + ro + dt * 16 + g * 4) = o;
      }
    }
  }
}

// ---------------------------------------------------------------------------
// K3: O-projection (r12 proj_body bf16 path, verbatim — proven, ~8 us).
// ---------------------------------------------------------------------------
__global__ __launch_bounds__(256, 4) void o_proj(
    const unsigned short* __restrict__ Ab, const unsigned short* __restrict__ WoT,
    const int* __restrict__ seq_lens, float* __restrict__ outf,
    const float* __restrict__ bo)
{
  constexpr int KDIM = 512, NCOLS = 128;
  constexpr int WC = NCOLS / 4;
  constexpr int NCT = WC / 16;
  constexpr int KSTEPS = KDIM / 32;
  constexpr int ASZ = 64 * 40 * 2;
  const int t = threadIdx.x;
  const int wid = t >> 6, lane = t & 63;
  const int q = lane & 15, g = lane >> 4;
  const int row0 = blockIdx.x * 64;
  const int wcol = blockIdx.y * NCOLS + wid * WC;

  const int sl = seq_lens[row0 >> 13];
  if ((row0 & 8191) >= sl) {
    if (blockIdx.y == 0) {
      f32x4 z = {0.f, 0.f, 0.f, 0.f};
      float* o = outf + (size_t)row0 * 256;
      #pragma unroll
      for (int i = 0; i < 16; ++i)
        *(f32x4*)(o + (size_t)(i * 256 + t) * 4) = z;
    }
    return;
  }

  __shared__ __align__(16) char smem[2 * ASZ];

  const int br0 = t >> 2, bkc = (t & 3) * 8;

  f32x4 acc[4][NCT];
  #pragma unroll
  for (int i = 0; i < 4; ++i)
    #pragma unroll
    for (int j = 0; j < NCT; ++j) acc[i][j] = {0.f, 0.f, 0.f, 0.f};

  u16x8 ab;
  ab = *(const u16x8*)(Ab + (size_t)(row0 + br0) * KDIM + bkc);
  *(u16x8*)((unsigned short*)smem + br0 * 40 + bkc) = ab;
  bf16x8 bcur[NCT];
  #pragma unroll
  for (int ct = 0; ct < NCT; ++ct)
    bcur[ct] = asbf8(*(const u16x8*)(WoT + (size_t)(wcol + ct * 16 + q) * KDIM + g * 8));
  __syncthreads();

  #pragma unroll 2
  for (int st = 0; st < KSTEPS; ++st) {
    const int cur = st & 1;
    const int k1 = (st + 1) * 32;

    if (st + 1 < KSTEPS)
      ab = *(const u16x8*)(Ab + (size_t)(row0 + br0) * KDIM + k1 + bkc);
    bf16x8 bnx[NCT];
    if (st + 1 < KSTEPS) {
      #pragma unroll
      for (int ct = 0; ct < NCT; ++ct)
        bnx[ct] = asbf8(*(const u16x8*)(WoT + (size_t)(wcol + ct * 16 + q) * KDIM + k1 + g * 8));
    }

    bf16x8 af[4];
    {
      const unsigned short* Lb = (const unsigned short*)(smem + cur * ASZ);
      #pragma unroll
      for (int rt = 0; rt < 4; ++rt)
        af[rt] = asbf8(*(const u16x8*)(Lb + (rt * 16 + q) * 40 + g * 8));
    }

    #pragma unroll
    for (int ct = 0; ct < NCT; ++ct)
      #pragma unroll
      for (int rt = 0; rt < 4; ++rt)
        acc[rt][ct] = MFMA(af[rt], bcur[ct], acc[rt][ct]);

    if (st + 1 < KSTEPS) {
      *(u16x8*)((unsigned short*)(smem + (cur ^ 1) * ASZ) + br0 * 40 + bkc) = ab;
      #pragma unroll
      for (int ct = 0; ct < NCT; ++ct) bcur[ct] = bnx[ct];
    }
    __syncthreads();
  }

  const int l0 = row0 & 8191;
  #pragma unroll
  for (int ct = 0; ct < NCT; ++ct) {
    int col = wcol + ct * 16 + q;
    float bias = bo[col];
    #pragma unroll
    for (int rt = 0; rt < 4; ++rt)
      #pragma unroll
      for (int r = 0; r < 4; ++r) {
        int ll = l0 + rt * 16 + g * 4 + r;
        float v = acc[rt][ct][r] + bias;
        outf[(size_t)(row0 + rt * 16 + g * 4 + r) * 256 + col] = (ll < sl) ? v : 0.f;
      }
  }
}

// ---------------------------------------------------------------------------
extern "C" void kernel_launch(void* const* d_in, const int* in_sizes, int n_in,
                              void* d_out, int out_size, void* d_ws, size_t ws_size,
                              hipStream_t stream) {
  const float* x   = (const float*)d_in[0];
  const float* ctx = (const float*)d_in[1];
  const int*   seq = (const int*)d_in[2];
  const float* Wq  = (const float*)d_in[3];
  const float* Wk  = (const float*)d_in[4];
  const float* Wv  = (const float*)d_in[5];
  const float* Wo  = (const float*)d_in[6];
  const float* bo  = (const float*)d_in[7];
  float* Y = (float*)d_out;

  unsigned short* ws = (unsigned short*)d_ws;
  unsigned short* WqT  = ws;                        // 512*256      = 131072
  unsigned short* WkvT = WqT + 131072;              // 1024*768     = 786432
  unsigned short* WoT  = WkvT + 786432;             // 256*512      = 131072
  unsigned short* Kws  = WoT + 131072;              // 8*8*512*64   = 2097152
  unsigned short* VTws = Kws + 2097152;             // 8*8*64*512   = 2097152
  unsigned short* AOws = VTws + 2097152;            // 8*8192*512   = 33554432

  convert_weights<<<4096, 256, 0, stream>>>(Wq, Wk, Wv, Wo, WqT, WkvT, WoT);

  // KV projection only (Q is fused into attention): 512 blocks
  kv_proj<<<512, 256, 0, stream>>>(ctx, WkvT, Kws, VTws);

  // Fused Q-compute + attention: 4096 items, XCD class (b+tile)&7
  attn_kernel<<<4096, 256, 0, stream>>>(x, WqT, Kws, VTws, seq, AOws);

  // Output projection + bias + mask   (N split in 2)
  o_proj<<<dim3(1024, 2), 256, 0, stream>>>(AOws, WoT, seq, Y, bo);
}

// Round 23
// 142.580 us; speedup vs baseline: 1.2015x; 1.2015x over previous
//
#include <hip/hip_runtime.h>
#include <hip/hip_bf16.h>

#define DEV __device__ __forceinline__

typedef float f32x4 __attribute__((ext_vector_type(4)));
typedef unsigned short u16x4 __attribute__((ext_vector_type(4)));
typedef unsigned short u16x8 __attribute__((ext_vector_type(8)));
typedef __bf16 bf16x8 __attribute__((ext_vector_type(8)));

DEV unsigned short f2b(float f) { __bf16 h = (__bf16)f; return __builtin_bit_cast(unsigned short, h); }
DEV bf16x8 asbf8(u16x8 v) { return __builtin_bit_cast(bf16x8, v); }

#define MFMA(a, b, c) __builtin_amdgcn_mfma_f32_16x16x32_bf16((a), (b), (c), 0, 0, 0)

// Problem constants
// B=8, L=8192, S=512, DQ=256, DC=768, H=8, DH=64, INNER=512
// QSCALE = (1/sqrt(64)) * log2(e): scores computed directly in log2 domain.
constexpr float QSCALE = 0.18033688011112042f;
// Fixed softmax shift (log2 domain), folded into the QK^T accumulator init.
constexpr float MFIX = 20.0f;

// ---------------------------------------------------------------------------
// K0: weight convert/transpose to bf16.
// ---------------------------------------------------------------------------
__global__ __launch_bounds__(256) void convert_weights(
    const float* __restrict__ Wq, const float* __restrict__ Wk,
    const float* __restrict__ Wv, const float* __restrict__ Wo,
    unsigned short* __restrict__ WqT, unsigned short* __restrict__ WkvT,
    unsigned short* __restrict__ WoT)
{
  int i = blockIdx.x * 256 + threadIdx.x;
  if (i < 131072) {
    int n = i >> 8, k = i & 255;                 // WqT [512][256]
    WqT[i] = f2b(Wq[k * 512 + n] * QSCALE);
  } else if (i < 131072 + 786432) {
    int j = i - 131072;
    int n = j / 768, k = j - n * 768;            // WkvT [1024][768]
    float v = (n < 512) ? Wk[k * 512 + n] : Wv[k * 512 + (n - 512)];
    WkvT[j] = f2b(v);
  } else {
    int j = i - 917504;
    int n = j >> 9, k = j & 511;                 // WoT [256][512]
    WoT[j] = f2b(Wo[k * 256 + n]);
  }
}

// ---------------------------------------------------------------------------
// Q/KV projection body (r17/r20 proven chunk-staged structure): coalesced
// stage of the whole 64x256 A-chunk to bf16 LDS (convert once), ONE barrier
// pair per chunk, then 8 barrier-free MFMA steps. LDS [64][264] u16.
// launch_bounds(256,4): 33.8KB x 4 = 135KB <= 160KB/CU; NCOLS=128 keeps
// unified regs ~96 << 128 cap (no spill; measured VGPR 56).
// ---------------------------------------------------------------------------
template<int KDIM, int NCOLS, int EPI>
DEV void proj_staged(int bx, int by, unsigned short* __restrict__ Lb,
                     const float* __restrict__ Af,
                     const unsigned short* __restrict__ BT,
                     const int* __restrict__ seq_lens,
                     unsigned short* __restrict__ out0,
                     unsigned short* __restrict__ out1)
{
  constexpr int WC = NCOLS / 4;
  constexpr int NCT = WC / 16;
  constexpr int NCH = KDIM / 256;       // 256-col chunks
  constexpr int RS = 264;               // u16 row stride (33x8 granules)
  const int t = threadIdx.x;
  const int wid = t >> 6, lane = t & 63;
  const int q = lane & 15, g = lane >> 4;
  const int row0 = bx * 64;
  const int wcol = by * NCOLS + wid * WC;

  if (EPI == 0) {
    const int sl = seq_lens[row0 >> 13];
    if ((row0 & 8191) >= sl) return;
  }

  // staging geometry: thread t covers rows ar0, ar0+32 at cols akc+32*stp
  const int ar0 = t >> 3, akc = (t & 7) * 4;

  const unsigned short* brow[NCT];
  #pragma unroll
  for (int ct = 0; ct < NCT; ++ct)
    brow[ct] = BT + (size_t)(wcol + ct * 16 + q) * KDIM + g * 8;

  f32x4 acc[4][NCT];
  #pragma unroll
  for (int i = 0; i < 4; ++i)
    #pragma unroll
    for (int j = 0; j < NCT; ++j) acc[i][j] = {0.f, 0.f, 0.f, 0.f};

  #pragma unroll 1
  for (int ch = 0; ch < NCH; ++ch) {
    const int kb = ch * 256;
    if (ch) __syncthreads();            // readers of previous chunk done

    // ---- stage A[64][256] chunk -> bf16 LDS (coalesced, convert once) ----
    #pragma unroll
    for (int stp = 0; stp < 8; ++stp) {
      const int col = akc + 32 * stp;
      f32x4 v0 = *(const f32x4*)(Af + (size_t)(row0 + ar0) * KDIM + kb + col);
      f32x4 v1 = *(const f32x4*)(Af + (size_t)(row0 + 32 + ar0) * KDIM + kb + col);
      u16x4 w0, w1;
      w0[0] = f2b(v0[0]); w0[1] = f2b(v0[1]); w0[2] = f2b(v0[2]); w0[3] = f2b(v0[3]);
      w1[0] = f2b(v1[0]); w1[1] = f2b(v1[1]); w1[2] = f2b(v1[2]); w1[3] = f2b(v1[3]);
      *(u16x4*)(Lb + ar0 * RS + col) = w0;
      *(u16x4*)(Lb + (32 + ar0) * RS + col) = w1;
    }
    __syncthreads();

    // ---- 8 barrier-free MFMA steps from LDS ------------------------------
    #pragma unroll
    for (int st = 0; st < 8; ++st) {
      const int k0 = st * 32;
      bf16x8 af[4];
      #pragma unroll
      for (int rt = 0; rt < 4; ++rt)
        af[rt] = asbf8(*(const u16x8*)(Lb + (rt * 16 + q) * RS + k0 + g * 8));
      bf16x8 bf[NCT];
      #pragma unroll
      for (int ct = 0; ct < NCT; ++ct)
        bf[ct] = asbf8(*(const u16x8*)(brow[ct] + kb + k0));
      #pragma unroll
      for (int ct = 0; ct < NCT; ++ct)
        #pragma unroll
        for (int rt = 0; rt < 4; ++rt)
          acc[rt][ct] = MFMA(af[rt], bf[ct], acc[rt][ct]);
    }
  }

  if (EPI == 0) {
    const int bb = row0 >> 13, l0 = row0 & 8191;
    #pragma unroll
    for (int ct = 0; ct < NCT; ++ct) {
      int col = wcol + ct * 16 + q;
      int hh = col >> 6, d = col & 63;
      unsigned short* o = out0 + (((size_t)bb * 8 + hh) * 8192) * 64 + d;
      #pragma unroll
      for (int rt = 0; rt < 4; ++rt)
        #pragma unroll
        for (int r = 0; r < 4; ++r) {
          int ll = l0 + rt * 16 + g * 4 + r;
          o[(size_t)ll * 64] = f2b(acc[rt][ct][r]);
        }
    }
  } else {
    const int bb = row0 >> 9, s0 = row0 & 511;
    #pragma unroll
    for (int ct = 0; ct < NCT; ++ct) {
      int col = wcol + ct * 16 + q;
      if (col < 512) {
        int hh = col >> 6, d = col & 63;
        #pragma unroll
        for (int rt = 0; rt < 4; ++rt)
          #pragma unroll
          for (int r = 0; r < 4; ++r) {
            int s = s0 + rt * 16 + g * 4 + r;
            out0[(((size_t)bb * 8 + hh) * 512 + s) * 64 + d] = f2b(acc[rt][ct][r]);
          }
      } else {
        int c2 = col - 512, hh = c2 >> 6, d = c2 & 63;
        #pragma unroll
        for (int rt = 0; rt < 4; ++rt)
          #pragma unroll
          for (int r = 0; r < 4; ++r) {
            int s = s0 + rt * 16 + g * 4 + r;
            out1[(((size_t)bb * 8 + hh) * 64 + d) * 512 + s] = f2b(acc[rt][ct][r]);
          }
      }
    }
  }
}

// ---------------------------------------------------------------------------
// K1: combined Q-proj + KV-proj (chunk-staged, 4 blocks/CU).
// bid < 512: KV (64 x 8) — same-bx blocks are 64 apart (64%8==0) -> already
// XCD-colocated. bid >= 512: Q — remapped so the 4 column-split blocks that
// share bx land on the SAME XCD (bids differ by multiples of 8):
//   bx = (j&7) | ((j>>5)<<3), by = (j>>3)&3   (bijective on [0,4096))
// -> x rows fetched once from HBM, splits hit local L2 (FETCH 93->34 MB).
// ---------------------------------------------------------------------------
__global__ __launch_bounds__(256, 4) void qkv_proj(
    const float* __restrict__ x, const float* __restrict__ ctx,
    const unsigned short* __restrict__ WqT, const unsigned short* __restrict__ WkvT,
    const int* __restrict__ seq_lens,
    unsigned short* __restrict__ Qws, unsigned short* __restrict__ Kws,
    unsigned short* __restrict__ VTws)
{
  __shared__ __align__(16) unsigned short Lb[64 * 264];   // 33.8 KB
  const int bid = blockIdx.x;
  if (bid < 512) {
    proj_staged<768, 128, 1>(bid & 63, bid >> 6, Lb,
                             ctx, WkvT, seq_lens, Kws, VTws);
  } else {
    const int j = bid - 512;
    const int bx = (j & 7) | ((j >> 5) << 3);
    const int by = (j >> 3) & 3;
    proj_staged<256, 128, 0>(bx, by, Lb,
                             x, WqT, seq_lens, Qws, nullptr);
  }
}

// ---------------------------------------------------------------------------
// K3: O-projection (r12 proj_body bf16 path, verbatim — proven, ~8 us).
// ---------------------------------------------------------------------------
__global__ __launch_bounds__(256, 4) void o_proj(
    const unsigned short* __restrict__ Ab, const unsigned short* __restrict__ WoT,
    const int* __restrict__ seq_lens, float* __restrict__ outf,
    const float* __restrict__ bo)
{
  constexpr int KDIM = 512, NCOLS = 128;
  constexpr int WC = NCOLS / 4;
  constexpr int NCT = WC / 16;
  constexpr int KSTEPS = KDIM / 32;
  constexpr int ASZ = 64 * 40 * 2;
  const int t = threadIdx.x;
  const int wid = t >> 6, lane = t & 63;
  const int q = lane & 15, g = lane >> 4;
  const int row0 = blockIdx.x * 64;
  const int wcol = blockIdx.y * NCOLS + wid * WC;

  const int sl = seq_lens[row0 >> 13];
  if ((row0 & 8191) >= sl) {
    if (blockIdx.y == 0) {
      f32x4 z = {0.f, 0.f, 0.f, 0.f};
      float* o = outf + (size_t)row0 * 256;
      #pragma unroll
      for (int i = 0; i < 16; ++i)
        *(f32x4*)(o + (size_t)(i * 256 + t) * 4) = z;
    }
    return;
  }

  __shared__ __align__(16) char smem[2 * ASZ];

  const int br0 = t >> 2, bkc = (t & 3) * 8;

  f32x4 acc[4][NCT];
  #pragma unroll
  for (int i = 0; i < 4; ++i)
    #pragma unroll
    for (int j = 0; j < NCT; ++j) acc[i][j] = {0.f, 0.f, 0.f, 0.f};

  u16x8 ab;
  ab = *(const u16x8*)(Ab + (size_t)(row0 + br0) * KDIM + bkc);
  *(u16x8*)((unsigned short*)smem + br0 * 40 + bkc) = ab;
  bf16x8 bcur[NCT];
  #pragma unroll
  for (int ct = 0; ct < NCT; ++ct)
    bcur[ct] = asbf8(*(const u16x8*)(WoT + (size_t)(wcol + ct * 16 + q) * KDIM + g * 8));
  __syncthreads();

  #pragma unroll 2
  for (int st = 0; st < KSTEPS; ++st) {
    const int cur = st & 1;
    const int k1 = (st + 1) * 32;

    if (st + 1 < KSTEPS)
      ab = *(const u16x8*)(Ab + (size_t)(row0 + br0) * KDIM + k1 + bkc);
    bf16x8 bnx[NCT];
    if (st + 1 < KSTEPS) {
      #pragma unroll
      for (int ct = 0; ct < NCT; ++ct)
        bnx[ct] = asbf8(*(const u16x8*)(WoT + (size_t)(wcol + ct * 16 + q) * KDIM + k1 + g * 8));
    }

    bf16x8 af[4];
    {
      const unsigned short* Lb = (const unsigned short*)(smem + cur * ASZ);
      #pragma unroll
      for (int rt = 0; rt < 4; ++rt)
        af[rt] = asbf8(*(const u16x8*)(Lb + (rt * 16 + q) * 40 + g * 8));
    }

    #pragma unroll
    for (int ct = 0; ct < NCT; ++ct)
      #pragma unroll
      for (int rt = 0; rt < 4; ++rt)
        acc[rt][ct] = MFMA(af[rt], bcur[ct], acc[rt][ct]);

    if (st + 1 < KSTEPS) {
      *(u16x8*)((unsigned short*)(smem + (cur ^ 1) * ASZ) + br0 * 40 + bkc) = ab;
      #pragma unroll
      for (int ct = 0; ct < NCT; ++ct) bcur[ct] = bnx[ct];
    }
    __syncthreads();
  }

  const int l0 = row0 & 8191;
  #pragma unroll
  for (int ct = 0; ct < NCT; ++ct) {
    int col = wcol + ct * 16 + q;
    float bias = bo[col];
    #pragma unroll
    for (int rt = 0; rt < 4; ++rt)
      #pragma unroll
      for (int r = 0; r < 4; ++r) {
        int ll = l0 + rt * 16 + g * 4 + r;
        float v = acc[rt][ct][r] + bias;
        outf[(size_t)(row0 + rt * 16 + g * 4 + r) * 256 + col] = (ll < sl) ? v : 0.f;
      }
  }
}

// ---------------------------------------------------------------------------
// K2: fused attention — r14 kernel verbatim (best measured: 61.8 us).
// KVBLK=32, 16 KB LDS, qt=2, one block per (b,h,128-row) item, early-exit,
// launch_bounds(256,4): 4 blocks/CU (64 KB LDS ceiling), VGPR 60, no spill.
// ---------------------------------------------------------------------------
__global__ __launch_bounds__(256, 4) void attn_kernel(
    const unsigned short* __restrict__ Qw, const unsigned short* __restrict__ Kw,
    const unsigned short* __restrict__ VTw, const int* __restrict__ seq_lens,
    unsigned short* __restrict__ AO)
{
  const int bid = blockIdx.x;
  const int h = bid & 7;                  // XCD class
  const int tile = (bid >> 3) & 63;       // 128-row tile index
  const int b = bid >> 9;                 // batch

  const int sl = seq_lens[b];
  const int qbase0 = tile * 128;
  if (qbase0 >= sl) return;               // dead item: exit immediately

  const int wid = threadIdx.x >> 6, lane = threadIdx.x & 63;
  const int q = lane & 15, g = lane >> 4;

  __shared__ __align__(16) unsigned short Ks[2][32 * 64];
  __shared__ __align__(16) unsigned short Vs[2][64 * 32];

  // staging geometry (identical to r4/r7 per 32-key tile)
  const int krow  = (wid << 3) + (lane >> 3);          // K row 0..31
  const int kslot = (lane & 7) ^ (lane >> 3);          // stored 16B slot (swz)
  const int vd    = (wid << 4) + (lane >> 2);          // V d-row 0..63
  const int vc    = lane & 3;                          // natural 8-elem chunk
  const int vswz  = (vd >> 1) & 3;
  const int vs0   = (((2 * vc) & 3) ^ vswz) * 8 + ((vc >> 1) * 4);      // elems
  const int vs1   = (((2 * vc + 1) & 3) ^ vswz) * 8 + ((vc >> 1) * 4);  // elems
  const int vrslot = (g ^ ((q >> 1) & 3)) * 8;         // va stored slot (elems)

  const int qbase = qbase0 + wid * 32;
  const bool wactive = qbase < sl;

  const unsigned short* Qb = Qw + (((size_t)b * 8 + h) * 8192 + qbase) * 64;
  const unsigned short* Kb = Kw + ((size_t)b * 8 + h) * (512 * 64);
  const unsigned short* Vb = VTw + ((size_t)b * 8 + h) * (64 * 512);

  bf16x8 qf[2][2];
  if (wactive) {
    #pragma unroll
    for (int qt = 0; qt < 2; ++qt)
      #pragma unroll
      for (int dc = 0; dc < 2; ++dc)
        qf[qt][dc] = asbf8(*(const u16x8*)(Qb + (qt * 16 + q) * 64 + dc * 32 + g * 8));
  }

  f32x4 acc[2][4];
  float lsum[2] = {0.f, 0.f};
  #pragma unroll
  for (int qt = 0; qt < 2; ++qt)
    #pragma unroll
    for (int dt = 0; dt < 4; ++dt) acc[qt][dt] = {0.f, 0.f, 0.f, 0.f};

  // ---- prologue: stage step 0 into buffer 0 -------------------------------
  {
    u16x8 kr = *(const u16x8*)(Kb + krow * 64 + (lane & 7) * 8);
    u16x8 vr = *(const u16x8*)(Vb + vd * 512 + vc * 8);
    *(u16x8*)(&Ks[0][krow * 64 + kslot * 8]) = kr;
    u16x4 vlo, vhi;
    vlo[0] = vr[0]; vlo[1] = vr[1]; vlo[2] = vr[2]; vlo[3] = vr[3];
    vhi[0] = vr[4]; vhi[1] = vr[5]; vhi[2] = vr[6]; vhi[3] = vr[7];
    *(u16x4*)(&Vs[0][vd * 32 + vs0]) = vlo;
    *(u16x4*)(&Vs[0][vd * 32 + vs1]) = vhi;
  }
  __syncthreads();

  #pragma unroll 2
  for (int st = 0; st < 16; ++st) {
    const int cur = st & 1;
    const int scn = (st + 1) * 32;

    u16x8 kn, vn;
    if (st < 15) {
      kn = *(const u16x8*)(Kb + (scn + krow) * 64 + (lane & 7) * 8);
      vn = *(const u16x8*)(Vb + vd * 512 + scn + vc * 8);
    }

    if (wactive) {
      bf16x8 kf[2][2];
      #pragma unroll
      for (int tt = 0; tt < 2; ++tt)
        #pragma unroll
        for (int dc = 0; dc < 2; ++dc)
          kf[tt][dc] = asbf8(*(const u16x8*)(
              &Ks[cur][(tt * 16 + q) * 64 + ((dc * 4 + g) ^ (q & 7)) * 8]));

      bf16x8 va[4];
      #pragma unroll
      for (int dt = 0; dt < 4; ++dt)
        va[dt] = asbf8(*(const u16x8*)(&Vs[cur][(dt * 16 + q) * 32 + vrslot]));

      #pragma unroll
      for (int qt = 0; qt < 2; ++qt) {
        f32x4 t0 = {-MFIX, -MFIX, -MFIX, -MFIX};
        f32x4 t1 = {-MFIX, -MFIX, -MFIX, -MFIX};
        t0 = MFMA(kf[0][0], qf[qt][0], t0);
        t0 = MFMA(kf[0][1], qf[qt][1], t0);
        t1 = MFMA(kf[1][0], qf[qt][0], t1);
        t1 = MFMA(kf[1][1], qf[qt][1], t1);

        float p0 = __builtin_amdgcn_exp2f(t0[0]);
        float p1 = __builtin_amdgcn_exp2f(t0[1]);
        float p2 = __builtin_amdgcn_exp2f(t0[2]);
        float p3 = __builtin_amdgcn_exp2f(t0[3]);
        float p4 = __builtin_amdgcn_exp2f(t1[0]);
        float p5 = __builtin_amdgcn_exp2f(t1[1]);
        float p6 = __builtin_amdgcn_exp2f(t1[2]);
        float p7 = __builtin_amdgcn_exp2f(t1[3]);
        lsum[qt] += ((p0 + p1) + (p2 + p3)) + ((p4 + p5) + (p6 + p7));

        u16x8 pu;
        pu[0] = f2b(p0); pu[1] = f2b(p1); pu[2] = f2b(p2); pu[3] = f2b(p3);
        pu[4] = f2b(p4); pu[5] = f2b(p5); pu[6] = f2b(p6); pu[7] = f2b(p7);
        bf16x8 pb = asbf8(pu);

        #pragma unroll
        for (int dt = 0; dt < 4; ++dt)
          acc[qt][dt] = MFMA(va[dt], pb, acc[qt][dt]);
      }
    }

    if (st < 15) {
      const int nb = cur ^ 1;
      *(u16x8*)(&Ks[nb][krow * 64 + kslot * 8]) = kn;
      u16x4 vlo, vhi;
      vlo[0] = vn[0]; vlo[1] = vn[1]; vlo[2] = vn[2]; vlo[3] = vn[3];
      vhi[0] = vn[4]; vhi[1] = vn[5]; vhi[2] = vn[6]; vhi[3] = vn[7];
      *(u16x4*)(&Vs[nb][vd * 32 + vs0]) = vlo;
      *(u16x4*)(&Vs[nb][vd * 32 + vs1]) = vhi;
    }
    __syncthreads();
  }

  if (wactive) {
    #pragma unroll
    for (int qt = 0; qt < 2; ++qt) {
      float lt = lsum[qt];
      lt += __shfl_xor(lt, 16);
      lt += __shfl_xor(lt, 32);
      float inv = __builtin_amdgcn_rcpf(lt);
      size_t ro = ((size_t)b * 8192 + qbase + qt * 16 + q) * 512 + h * 64;
      #pragma unroll
      for (int dt = 0; dt < 4; ++dt) {
        u16x4 o;
        o[0] = f2b(acc[qt][dt][0] * inv);
        o[1] = f2b(acc[qt][dt][1] * inv);
        o[2] = f2b(acc[qt][dt][2] * inv);
        o[3] = f2b(acc[qt][dt][3] * inv);
        *(u16x4*)(AO + ro + dt * 16 + g * 4) = o;
      }
    }
  }
}

// ---------------------------------------------------------------------------
extern "C" void kernel_launch(void* const* d_in, const int* in_sizes, int n_in,
                              void* d_out, int out_size, void* d_ws, size_t ws_size,
                              hipStream_t stream) {
  const float* x   = (const float*)d_in[0];
  const float* ctx = (const float*)d_in[1];
  const int*   seq = (const int*)d_in[2];
  const float* Wq  = (const float*)d_in[3];
  const float* Wk  = (const float*)d_in[4];
  const float* Wv  = (const float*)d_in[5];
  const float* Wo  = (const float*)d_in[6];
  const float* bo  = (const float*)d_in[7];
  float* Y = (float*)d_out;

  unsigned short* ws = (unsigned short*)d_ws;
  unsigned short* WqT  = ws;                        // 512*256      = 131072
  unsigned short* WkvT = WqT + 131072;              // 1024*768     = 786432
  unsigned short* WoT  = WkvT + 786432;             // 256*512      = 131072
  unsigned short* Qws  = WoT + 131072;              // 8*8*8192*64  = 33554432
  unsigned short* Kws  = Qws + 33554432;            // 8*8*512*64   = 2097152
  unsigned short* VTws = Kws + 2097152;             // 8*8*64*512   = 2097152
  unsigned short* AOws = VTws + 2097152;            // 8*8192*512   = 33554432

  convert_weights<<<4096, 256, 0, stream>>>(Wq, Wk, Wv, Wo, WqT, WkvT, WoT);

  // Combined Q-proj + KV-proj: chunk-staged, 4 blocks/CU, XCD-local Q splits
  qkv_proj<<<4608, 256, 0, stream>>>(x, ctx, WqT, WkvT, seq, Qws, Kws, VTws);

  // Attention: KVBLK=32, one block per (b,h,128-row) item, 4 blocks/CU
  attn_kernel<<<4096, 256, 0, stream>>>(Qws, Kws, VTws, seq, AOws);

  // Output projection + bias + mask   (N split in 2)
  o_proj<<<dim3(1024, 2), 256, 0, stream>>>(AOws, WoT, seq, Y, bo);
}